// Round 12
// baseline (451.149 us; speedup 1.0000x reference)
//
#include <hip/hip_runtime.h>

// ---------------------------------------------------------------------------
// meta_model: out = (w0*sig(Ll Ll^T) + w1*sig((La La^T)*aa) + w2*sig((Lm Lm^T)*mod)
//                    - sig(Lu Lu^T)) * adj + sig(Lu Lu^T)
// with L* = mlp(feat), w = softmax(ws)
//
// R11: maximum-TLP k_ctx. Ten rounds of scheduling pinned at 2.2-2.9 TB/s;
// best-ever effective BW was R1's simple kernel at 16 waves/CU. Loaded
// latency is queueing-dominated -> wave count, not per-wave depth, is the
// remaining lever:
//   - ew loads straight to REGISTERS via asm (cannot be sunk - R9-proven),
//     double-buffered across steps (full-step cover), no ew LDS at all
//   - fj g-sequential in regs (32 VGPR, 1-gram lookahead, 4 counted waits
//     per step) instead of 16-frag dbuf (128 VGPR)
//   - fi in 16KB block-shared LDS (4 waves share one 16-row block, R9 map)
//   - VGPR ~110 -> launch_bounds(256,4): 16 waves/CU, 4 blocks/CU, ZERO
//     in-loop barriers; per-CU in-flight ~ 16 waves x 7KB = 112KB
//   - grid 2048 = 512 rowblocks x 4 colstrips (R9 mapping)
// ---------------------------------------------------------------------------

typedef __attribute__((ext_vector_type(8))) short short8;
typedef __attribute__((ext_vector_type(4))) float f32x4;

__device__ __forceinline__ unsigned short f2bf(float x) {
  union { float f; unsigned u; } v; v.f = x;
  unsigned u = v.u + 0x7FFFu + ((v.u >> 16) & 1u);   // round-to-nearest-even
  return (unsigned short)(u >> 16);
}

__device__ __forceinline__ float sigf(float x) {
  float e = __builtin_amdgcn_exp2f(-1.4426950408889634f * x);
  return __builtin_amdgcn_rcpf(1.0f + e);
}

__device__ __forceinline__ void gload_lds16u(const unsigned short* g, unsigned short* l) {
  __builtin_amdgcn_global_load_lds(
      (const __attribute__((address_space(1))) void*)g,
      (__attribute__((address_space(3))) void*)l, 16, 0, 0);
}

__device__ __forceinline__ unsigned lds_off(const void* p) {
  return (unsigned)(uintptr_t)(const __attribute__((address_space(3))) void*)p;
}
__device__ __forceinline__ short8 ds_read_frag(unsigned a) {
  short8 d;
  asm volatile("ds_read_b128 %0, %1" : "=v"(d) : "v"(a));
  return d;
}

// --------------------------- stage A0: feat -> frag -------------------------
__global__ __launch_bounds__(256) void k_featfrag(const float* __restrict__ feat,
                                                  unsigned short* __restrict__ dst) {
  int t = blockIdx.x * 256 + threadIdx.x;   // 8192 rows * 64 chunks
  int row = t >> 6, kc = t & 63;            // 8 cols per thread
  const float4* s = reinterpret_cast<const float4*>(feat + row * 512 + kc * 8);
  float4 v0 = s[0], v1 = s[1];
  short8 o;
  o[0] = f2bf(v0.x); o[1] = f2bf(v0.y); o[2] = f2bf(v0.z); o[3] = f2bf(v0.w);
  o[4] = f2bf(v1.x); o[5] = f2bf(v1.y); o[6] = f2bf(v1.z); o[7] = f2bf(v1.w);
  int mb = row >> 4, kk = kc >> 2;
  int lane = ((kc & 3) << 4) | (row & 15);
  *reinterpret_cast<short8*>(dst + ((size_t)((mb * 16 + kk) * 64 + lane)) * 8) = o;
}

// --------------------- stage A0w: W1/W2 -> B-frag layout ---------------------
__global__ __launch_bounds__(256) void k_wfrag(
    const float* __restrict__ w1_0, const float* __restrict__ w1_1,
    const float* __restrict__ w1_2, const float* __restrict__ w1_3,
    const float* __restrict__ w2_0, const float* __restrict__ w2_1,
    const float* __restrict__ w2_2, const float* __restrict__ w2_3,
    unsigned short* __restrict__ w1f, unsigned short* __restrict__ w2f) {
  int t = blockIdx.x * 256 + threadIdx.x;
  if (t < 32768) {  // W1frag: [g][kk=16][nb=8][lane=64][j=8]
    int lane = t & 63, nb = (t >> 6) & 7, kk = (t >> 9) & 15, g = t >> 13;
    const float* W = g == 0 ? w1_0 : g == 1 ? w1_1 : g == 2 ? w1_2 : w1_3;
    int q = lane >> 4, r = lane & 15;
    int col = nb * 16 + r;
    short8 o;
#pragma unroll
    for (int j = 0; j < 8; ++j) o[j] = f2bf(W[(kk * 32 + q * 8 + j) * 128 + col]);
    *reinterpret_cast<short8*>(w1f + (size_t)t * 8) = o;
  } else if (t < 40960) {  // W2frag: [g][kk=4][nb=8][lane=64][j=8]
    int t2 = t - 32768;
    int lane = t2 & 63, nb = (t2 >> 6) & 7, kk = (t2 >> 9) & 3, g = t2 >> 11;
    const float* W = g == 0 ? w2_0 : g == 1 ? w2_1 : g == 2 ? w2_2 : w2_3;
    int q = lane >> 4, r = lane & 15;
    int col = nb * 16 + r;
    short8 o;
#pragma unroll
    for (int j = 0; j < 8; ++j) o[j] = f2bf(W[(kk * 32 + q * 8 + j) * 128 + col]);
    *reinterpret_cast<short8*>(w2f + (size_t)t2 * 8) = o;
  }
}

// --------------------- stage A1: H = relu(feat@W1cat + b1) -------------------
__global__ __launch_bounds__(256) void k_gemm1(
    const unsigned short* __restrict__ featf, const unsigned short* __restrict__ w1f,
    const float* __restrict__ b1_0, const float* __restrict__ b1_1,
    const float* __restrict__ b1_2, const float* __restrict__ b1_3,
    unsigned short* __restrict__ hfrag) {
  int bi = blockIdx.x, g = blockIdx.y;
  int lane = threadIdx.x & 63, w = threadIdx.x >> 6;
  int wm = w >> 1, wn = w & 1;
  int q = lane >> 4, r = lane & 15;
  int mbase = 8 * bi + 4 * wm;

  f32x4 s[4][4];
#pragma unroll
  for (int mi = 0; mi < 4; ++mi)
#pragma unroll
    for (int nj = 0; nj < 4; ++nj) s[mi][nj] = (f32x4){0.f, 0.f, 0.f, 0.f};

  for (int kk = 0; kk < 16; ++kk) {
    short8 a[4], b[4];
#pragma unroll
    for (int mi = 0; mi < 4; ++mi)
      a[mi] = *reinterpret_cast<const short8*>(
          featf + ((size_t)(((mbase + mi) * 16 + kk) * 64 + lane)) * 8);
#pragma unroll
    for (int nj = 0; nj < 4; ++nj)
      b[nj] = *reinterpret_cast<const short8*>(
          w1f + ((size_t)(((g * 16 + kk) * 8 + 4 * wn + nj) * 64 + lane)) * 8);
#pragma unroll
    for (int mi = 0; mi < 4; ++mi)
#pragma unroll
      for (int nj = 0; nj < 4; ++nj)
        s[mi][nj] = __builtin_amdgcn_mfma_f32_16x16x32_bf16(a[mi], b[nj], s[mi][nj], 0, 0, 0);
  }

  const float* b1 = g == 0 ? b1_0 : g == 1 ? b1_1 : g == 2 ? b1_2 : b1_3;
#pragma unroll
  for (int nj = 0; nj < 4; ++nj) {
    int cl = 64 * wn + 16 * nj + r;
    float bias = b1[cl];
    int Cg = 128 * g + cl;
    int kkd = Cg >> 5;
    int lane2hi = ((Cg >> 3) & 3) << 4;
    int j2 = Cg & 7;
#pragma unroll
    for (int mi = 0; mi < 4; ++mi) {
#pragma unroll
      for (int v = 0; v < 4; ++v) {
        int R = 128 * bi + 64 * wm + 16 * mi + 4 * q + v;
        float val = fmaxf(s[mi][nj][v] + bias, 0.0f);
        int mb = R >> 4;
        int lane2 = lane2hi | (R & 15);
        hfrag[((size_t)((mb * 16 + kkd) * 64 + lane2)) * 8 + j2] = f2bf(val);
      }
    }
  }
}

// --------------------- stage A2: lat_g = H_g@W2_g + b2 -----------------------
__global__ __launch_bounds__(256) void k_gemm2(
    const unsigned short* __restrict__ hfrag, const unsigned short* __restrict__ w2f,
    const float* __restrict__ b2_0, const float* __restrict__ b2_1,
    const float* __restrict__ b2_2, const float* __restrict__ b2_3,
    unsigned short* __restrict__ latf) {
  int bi = blockIdx.x, g = blockIdx.y;
  int lane = threadIdx.x & 63, w = threadIdx.x >> 6;
  int wm = w >> 1, wn = w & 1;
  int q = lane >> 4, r = lane & 15;
  int mbase = 8 * bi + 4 * wm;

  f32x4 s[4][4];
#pragma unroll
  for (int mi = 0; mi < 4; ++mi)
#pragma unroll
    for (int nj = 0; nj < 4; ++nj) s[mi][nj] = (f32x4){0.f, 0.f, 0.f, 0.f};

#pragma unroll
  for (int kk = 0; kk < 4; ++kk) {
    short8 a[4], b[4];
#pragma unroll
    for (int mi = 0; mi < 4; ++mi)
      a[mi] = *reinterpret_cast<const short8*>(
          hfrag + ((size_t)(((mbase + mi) * 16 + 4 * g + kk) * 64 + lane)) * 8);
#pragma unroll
    for (int nj = 0; nj < 4; ++nj)
      b[nj] = *reinterpret_cast<const short8*>(
          w2f + ((size_t)(((g * 4 + kk) * 8 + 4 * wn + nj) * 64 + lane)) * 8);
#pragma unroll
    for (int mi = 0; mi < 4; ++mi)
#pragma unroll
      for (int nj = 0; nj < 4; ++nj)
        s[mi][nj] = __builtin_amdgcn_mfma_f32_16x16x32_bf16(a[mi], b[nj], s[mi][nj], 0, 0, 0);
  }

  const float* b2 = g == 0 ? b2_0 : g == 1 ? b2_1 : g == 2 ? b2_2 : b2_3;
#pragma unroll
  for (int nj = 0; nj < 4; ++nj) {
    int cl = 64 * wn + 16 * nj + r;
    float bias = b2[cl];
    int kkd = cl >> 5;
    int lane2hi = ((cl >> 3) & 3) << 4;
    int j2 = cl & 7;
#pragma unroll
    for (int mi = 0; mi < 4; ++mi) {
#pragma unroll
      for (int v = 0; v < 4; ++v) {
        int R = 128 * bi + 64 * wm + 16 * mi + 4 * q + v;
        float val = s[mi][nj][v] + bias;
        int mb = R >> 4;
        int lane2 = lane2hi | (R & 15);
        latf[((size_t)(((g * 512 + mb) * 4 + kkd) * 64 + lane2)) * 8 + j2] = f2bf(val);
      }
    }
  }
}

// --------------------------- stage B: fused context --------------------------
// Block: 256 thr / 4 waves sharing one 16-row block (mb = bid>>2), strip
// cs = bid&3 (2048 cols), 32 steps x 64 cols; wave w owns tj = cs*128+s*4+w.
// s = mfma(fj, fi): lane(q,r) reg v -> out(16*mb + r, 16*tj + 4q + v).
// fi: 16KB LDS (block-shared). fj: per-gram reg loads (asm). ew: reg dbuf.
// NO in-loop barriers, NO ew LDS. 4 counted vmcnt waits/step.

#define VLD4(dst, p, OFF) \
  asm volatile("global_load_dwordx4 %0, %1, off offset:" OFF : "=v"(dst) : "v"(p))

#define LOADG(F, G)                                                           \
  do {                                                                        \
    const unsigned short* _p = fjbase + (size_t)(G) * GS;                     \
    VLD4(F[0], _p, "0");    VLD4(F[1], _p, "1024");                           \
    VLD4(F[2], _p, "2048"); VLD4(F[3], _p, "3072");                           \
  } while (0)

#define GRAMG(SG, F, G)                                                       \
  do {                                                                        \
    short8 _i0 = ds_read_frag(fib + ((G) * 4 + 0) * 1024u + l16);             \
    short8 _i1 = ds_read_frag(fib + ((G) * 4 + 1) * 1024u + l16);             \
    short8 _i2 = ds_read_frag(fib + ((G) * 4 + 2) * 1024u + l16);             \
    short8 _i3 = ds_read_frag(fib + ((G) * 4 + 3) * 1024u + l16);             \
    asm volatile("s_waitcnt lgkmcnt(0)" ::: "memory");                        \
    __builtin_amdgcn_sched_barrier(0);                                        \
    SG = (f32x4){0.f, 0.f, 0.f, 0.f};                                         \
    SG = __builtin_amdgcn_mfma_f32_16x16x32_bf16(F[0], _i0, SG, 0, 0, 0);     \
    SG = __builtin_amdgcn_mfma_f32_16x16x32_bf16(F[1], _i1, SG, 0, 0, 0);     \
    SG = __builtin_amdgcn_mfma_f32_16x16x32_bf16(F[2], _i2, SG, 0, 0, 0);     \
    SG = __builtin_amdgcn_mfma_f32_16x16x32_bf16(F[3], _i3, SG, 0, 0, 0);     \
  } while (0)

// One step. EWC: current ew regs (loaded >= 1 step ago). EWN: regs to load
// ew(s+1) into. Queue entering: [ew(s)=EWC 3, store(s-1) 1] (or fewer, s=0).
#define STEP(S, EWCa, EWCm, EWCj, EWNa, EWNm, EWNj)                           \
  do {                                                                        \
    const unsigned short* fjbase =                                            \
        latf + (size_t)(cb0 + (S) * 4 + w) * 2048 + (size_t)lane * 8;         \
    short8 fjA[4], fjB[4];                                                    \
    LOADG(fjA, 0);                                                            \
    LOADG(fjB, 1);                                                            \
    asm volatile("s_waitcnt vmcnt(4)" ::: "memory");  /* ew,store,fjA done */ \
    __builtin_amdgcn_sched_barrier(0);                                        \
    f32x4 sg, o4;                                                             \
    GRAMG(sg, fjA, 0);                                                        \
    LOADG(fjA, 2);                         /* g2 into fjA regs */             \
    o4[0] = w0 * sigf(sg[0]); o4[1] = w0 * sigf(sg[1]);                       \
    o4[2] = w0 * sigf(sg[2]); o4[3] = w0 * sigf(sg[3]);                       \
    asm volatile("s_waitcnt vmcnt(4)" ::: "memory");  /* fjB done */          \
    __builtin_amdgcn_sched_barrier(0);                                        \
    GRAMG(sg, fjB, 1);                                                        \
    LOADG(fjB, 3);                         /* g3 into fjB regs */             \
    o4[0] += w1 * sigf(sg[0] * EWCa[0]); o4[1] += w1 * sigf(sg[1] * EWCa[1]); \
    o4[2] += w1 * sigf(sg[2] * EWCa[2]); o4[3] += w1 * sigf(sg[3] * EWCa[3]); \
    asm volatile("s_waitcnt vmcnt(4)" ::: "memory");  /* fjA(g2) done */      \
    __builtin_amdgcn_sched_barrier(0);                                        \
    GRAMG(sg, fjA, 2);                                                        \
    { /* issue ew(s+1) now: full-step cover */                                \
      int _sn = ((S) + 1 < 32) ? (S) + 1 : (S);                               \
      const float* _ea = aa + ewoff + (size_t)_sn * 64;                       \
      const float* _em = mod + ewoff + (size_t)_sn * 64;                      \
      const float* _ej = adj + ewoff + (size_t)_sn * 64;                      \
      VLD4(EWNa, _ea, "0"); VLD4(EWNm, _em, "0"); VLD4(EWNj, _ej, "0");       \
    }                                                                         \
    o4[0] += w2 * sigf(sg[0] * EWCm[0]); o4[1] += w2 * sigf(sg[1] * EWCm[1]); \
    o4[2] += w2 * sigf(sg[2] * EWCm[2]); o4[3] += w2 * sigf(sg[3] * EWCm[3]); \
    asm volatile("s_waitcnt vmcnt(3)" ::: "memory");  /* fjB(g3) done */      \
    __builtin_amdgcn_sched_barrier(0);                                        \
    GRAMG(sg, fjB, 3);                                                        \
    f32x4 res;                                                                \
    {                                                                         \
      float u0 = sigf(sg[0]), u1 = sigf(sg[1]);                               \
      float u2 = sigf(sg[2]), u3 = sigf(sg[3]);                               \
      res[0] = EWCj[0] * (o4[0] - u0) + u0;                                   \
      res[1] = EWCj[1] * (o4[1] - u1) + u1;                                   \
      res[2] = EWCj[2] * (o4[2] - u2) + u2;                                   \
      res[3] = EWCj[3] * (o4[3] - u3) + u3;                                   \
    }                                                                         \
    {                                                                         \
      float* _op = out + ewoff + (size_t)(S) * 64;                            \
      asm volatile("global_store_dwordx4 %0, %1, off" ::"v"(_op), "v"(res)    \
                   : "memory");                                               \
    }                                                                         \
  } while (0)

__global__ __launch_bounds__(256, 4) void k_ctx(
    const unsigned short* __restrict__ latf,
    const float* __restrict__ adj, const float* __restrict__ aa,
    const float* __restrict__ mod, const float* __restrict__ wsv,
    float* __restrict__ out) {
  __shared__ unsigned short fi_lds[8192];   // 16 KB: 16 frags (4g x 4kk)

  const int bid = blockIdx.x;               // 2048 = 512 rowblocks x 4 strips
  const int cs = bid & 3;
  const int mb = bid >> 2;                  // 16-row block (0..511)
  const int lane = threadIdx.x & 63, w = threadIdx.x >> 6;
  const int q = lane >> 4, r = lane & 15;

  // softmax(ws)
  float s0w = wsv[0], s1w = wsv[1], s2w = wsv[2];
  float mx = fmaxf(fmaxf(s0w, s1w), s2w);
  float e0 = __builtin_amdgcn_exp2f(1.4426950408889634f * (s0w - mx));
  float e1 = __builtin_amdgcn_exp2f(1.4426950408889634f * (s1w - mx));
  float e2 = __builtin_amdgcn_exp2f(1.4426950408889634f * (s2w - mx));
  float inv = __builtin_amdgcn_rcpf(e0 + e1 + e2);
  float w0 = e0 * inv, w1 = e1 * inv, w2 = e2 * inv;

  const size_t GS = (size_t)512 * 2048;     // latf elements per latent
  const int cb0 = cs * 128;                 // first col-block of strip

  // ew per-lane offset: row = 16*mb + r, col = cs*2048 + 16w + 4q (+64/step)
  const size_t ewoff = (size_t)(mb * 16 + r) * 8192 + (size_t)cs * 2048
                     + (size_t)(16 * w + 4 * q);

  // ---- prologue: stage fi (wave w -> gram w's 4 frags), prime ew(0) ----
#pragma unroll
  for (int kk = 0; kk < 4; ++kk)
    gload_lds16u(latf + GS * w + (size_t)(mb * 4 + kk) * 512 + lane * 8,
                 &fi_lds[(w * 4 + kk) * 512]);

  f32x4 ewAa, ewAm, ewAj, ewBa, ewBm, ewBj;
  VLD4(ewAa, (aa + ewoff), "0");
  VLD4(ewAm, (mod + ewoff), "0");
  VLD4(ewAj, (adj + ewoff), "0");
  asm volatile("s_waitcnt vmcnt(0)" ::: "memory");
  __builtin_amdgcn_s_barrier();

  const unsigned fib = lds_off(fi_lds);
  const unsigned l16 = (unsigned)lane * 16u;

#pragma unroll 1
  for (int s = 0; s < 32; s += 2) {
    STEP(s, ewAa, ewAm, ewAj, ewBa, ewBm, ewBj);
    STEP(s + 1, ewBa, ewBm, ewBj, ewAa, ewAm, ewAj);
  }
}

// ------------------------------------------------------------------------------
extern "C" void kernel_launch(void* const* d_in, const int* in_sizes, int n_in,
                              void* d_out, int out_size, void* d_ws, size_t ws_size,
                              hipStream_t stream) {
  const float* feat = (const float*)d_in[0];
  const float* adj  = (const float*)d_in[1];
  const float* aa   = (const float*)d_in[2];
  const float* mod  = (const float*)d_in[3];
  // g order: 0=link, 1=aa, 2=mod, 3=unlink
  const float* W1g[4] = {(const float*)d_in[4], (const float*)d_in[12],
                         (const float*)d_in[16], (const float*)d_in[8]};
  const float* b1g[4] = {(const float*)d_in[5], (const float*)d_in[13],
                         (const float*)d_in[17], (const float*)d_in[9]};
  const float* W2g[4] = {(const float*)d_in[6], (const float*)d_in[14],
                         (const float*)d_in[18], (const float*)d_in[10]};
  const float* b2g[4] = {(const float*)d_in[7], (const float*)d_in[15],
                         (const float*)d_in[19], (const float*)d_in[11]};
  const float* wsv = (const float*)d_in[20];
  float* out = (float*)d_out;

  // workspace layout (elements of ushort)
  unsigned short* featf = (unsigned short*)d_ws;   // 4,194,304 elems (8 MiB)
  unsigned short* hfrag = featf + 4194304;         // 4,194,304
  unsigned short* latf  = hfrag + 4194304;         // 4,194,304
  unsigned short* w1f   = latf + 4194304;          //   262,144
  unsigned short* w2f   = w1f + 262144;            //    65,536
  if (ws_size < 25821184) return;

  k_featfrag<<<2048, 256, 0, stream>>>(feat, featf);
  k_wfrag<<<160, 256, 0, stream>>>(W1g[0], W1g[1], W1g[2], W1g[3],
                                   W2g[0], W2g[1], W2g[2], W2g[3], w1f, w2f);
  k_gemm1<<<dim3(64, 4), 256, 0, stream>>>(featf, w1f, b1g[0], b1g[1], b1g[2], b1g[3], hfrag);
  k_gemm2<<<dim3(64, 4), 256, 0, stream>>>(hfrag, w2f, b2g[0], b2g[1], b2g[2], b2g[3], latf);
  k_ctx<<<2048, 256, 0, stream>>>(latf, adj, aa, mod, wsv, out);
}

// Round 13
// 440.985 us; speedup vs baseline: 1.0230x; 1.0230x over previous
//
#include <hip/hip_runtime.h>

// ---------------------------------------------------------------------------
// meta_model: out = (w0*sig(Ll Ll^T) + w1*sig((La La^T)*aa) + w2*sig((Lm Lm^T)*mod)
//                    - sig(Lu Lu^T)) * adj + sig(Lu Lu^T)
// with L* = mlp(feat), w = softmax(ws)
//
// R12: combine the two proven-good halves that were never combined:
//   R9's one-phase-ahead fj prefetch (asm reg loads, counted waits, full
//   cover) x R11's high occupancy (4 waves/SIMD, no in-loop barriers).
//   Per step (one 16x16 tile, 4 gram phases):
//     phase0: issue fj(g1); vmcnt(8)  -> g0 (issued last phase3) ready
//     phase1: issue fj(g2); vmcnt(4)  -> g1 ready (1 phase of cover)
//     phase2: issue fj(g3); vmcnt(4)  -> g2 ready
//     phase3: issue fj(next g0) + ew(s+1); vmcnt(7) -> g3 ready; store
//   Entry invariant: 8 outstanding [F0(4), EW(3), ST(1)]. ew regs get a
//   full step of cover; every fj batch a full phase + 3 sibling waves.
// ---------------------------------------------------------------------------

typedef __attribute__((ext_vector_type(8))) short short8;
typedef __attribute__((ext_vector_type(4))) float f32x4;

__device__ __forceinline__ unsigned short f2bf(float x) {
  union { float f; unsigned u; } v; v.f = x;
  unsigned u = v.u + 0x7FFFu + ((v.u >> 16) & 1u);   // round-to-nearest-even
  return (unsigned short)(u >> 16);
}

__device__ __forceinline__ float sigf(float x) {
  float e = __builtin_amdgcn_exp2f(-1.4426950408889634f * x);
  return __builtin_amdgcn_rcpf(1.0f + e);
}

__device__ __forceinline__ void gload_lds16u(const unsigned short* g, unsigned short* l) {
  __builtin_amdgcn_global_load_lds(
      (const __attribute__((address_space(1))) void*)g,
      (__attribute__((address_space(3))) void*)l, 16, 0, 0);
}

__device__ __forceinline__ unsigned lds_off(const void* p) {
  return (unsigned)(uintptr_t)(const __attribute__((address_space(3))) void*)p;
}
__device__ __forceinline__ short8 ds_read_frag(unsigned a) {
  short8 d;
  asm volatile("ds_read_b128 %0, %1" : "=v"(d) : "v"(a));
  return d;
}

// --------------------------- stage A0: feat -> frag -------------------------
__global__ __launch_bounds__(256) void k_featfrag(const float* __restrict__ feat,
                                                  unsigned short* __restrict__ dst) {
  int t = blockIdx.x * 256 + threadIdx.x;   // 8192 rows * 64 chunks
  int row = t >> 6, kc = t & 63;            // 8 cols per thread
  const float4* s = reinterpret_cast<const float4*>(feat + row * 512 + kc * 8);
  float4 v0 = s[0], v1 = s[1];
  short8 o;
  o[0] = f2bf(v0.x); o[1] = f2bf(v0.y); o[2] = f2bf(v0.z); o[3] = f2bf(v0.w);
  o[4] = f2bf(v1.x); o[5] = f2bf(v1.y); o[6] = f2bf(v1.z); o[7] = f2bf(v1.w);
  int mb = row >> 4, kk = kc >> 2;
  int lane = ((kc & 3) << 4) | (row & 15);
  *reinterpret_cast<short8*>(dst + ((size_t)((mb * 16 + kk) * 64 + lane)) * 8) = o;
}

// --------------------- stage A0w: W1/W2 -> B-frag layout ---------------------
__global__ __launch_bounds__(256) void k_wfrag(
    const float* __restrict__ w1_0, const float* __restrict__ w1_1,
    const float* __restrict__ w1_2, const float* __restrict__ w1_3,
    const float* __restrict__ w2_0, const float* __restrict__ w2_1,
    const float* __restrict__ w2_2, const float* __restrict__ w2_3,
    unsigned short* __restrict__ w1f, unsigned short* __restrict__ w2f) {
  int t = blockIdx.x * 256 + threadIdx.x;
  if (t < 32768) {  // W1frag: [g][kk=16][nb=8][lane=64][j=8]
    int lane = t & 63, nb = (t >> 6) & 7, kk = (t >> 9) & 15, g = t >> 13;
    const float* W = g == 0 ? w1_0 : g == 1 ? w1_1 : g == 2 ? w1_2 : w1_3;
    int q = lane >> 4, r = lane & 15;
    int col = nb * 16 + r;
    short8 o;
#pragma unroll
    for (int j = 0; j < 8; ++j) o[j] = f2bf(W[(kk * 32 + q * 8 + j) * 128 + col]);
    *reinterpret_cast<short8*>(w1f + (size_t)t * 8) = o;
  } else if (t < 40960) {  // W2frag: [g][kk=4][nb=8][lane=64][j=8]
    int t2 = t - 32768;
    int lane = t2 & 63, nb = (t2 >> 6) & 7, kk = (t2 >> 9) & 3, g = t2 >> 11;
    const float* W = g == 0 ? w2_0 : g == 1 ? w2_1 : g == 2 ? w2_2 : w2_3;
    int q = lane >> 4, r = lane & 15;
    int col = nb * 16 + r;
    short8 o;
#pragma unroll
    for (int j = 0; j < 8; ++j) o[j] = f2bf(W[(kk * 32 + q * 8 + j) * 128 + col]);
    *reinterpret_cast<short8*>(w2f + (size_t)t2 * 8) = o;
  }
}

// --------------------- stage A1: H = relu(feat@W1cat + b1) -------------------
__global__ __launch_bounds__(256) void k_gemm1(
    const unsigned short* __restrict__ featf, const unsigned short* __restrict__ w1f,
    const float* __restrict__ b1_0, const float* __restrict__ b1_1,
    const float* __restrict__ b1_2, const float* __restrict__ b1_3,
    unsigned short* __restrict__ hfrag) {
  int bi = blockIdx.x, g = blockIdx.y;
  int lane = threadIdx.x & 63, w = threadIdx.x >> 6;
  int wm = w >> 1, wn = w & 1;
  int q = lane >> 4, r = lane & 15;
  int mbase = 8 * bi + 4 * wm;

  f32x4 s[4][4];
#pragma unroll
  for (int mi = 0; mi < 4; ++mi)
#pragma unroll
    for (int nj = 0; nj < 4; ++nj) s[mi][nj] = (f32x4){0.f, 0.f, 0.f, 0.f};

  for (int kk = 0; kk < 16; ++kk) {
    short8 a[4], b[4];
#pragma unroll
    for (int mi = 0; mi < 4; ++mi)
      a[mi] = *reinterpret_cast<const short8*>(
          featf + ((size_t)(((mbase + mi) * 16 + kk) * 64 + lane)) * 8);
#pragma unroll
    for (int nj = 0; nj < 4; ++nj)
      b[nj] = *reinterpret_cast<const short8*>(
          w1f + ((size_t)(((g * 16 + kk) * 8 + 4 * wn + nj) * 64 + lane)) * 8);
#pragma unroll
    for (int mi = 0; mi < 4; ++mi)
#pragma unroll
      for (int nj = 0; nj < 4; ++nj)
        s[mi][nj] = __builtin_amdgcn_mfma_f32_16x16x32_bf16(a[mi], b[nj], s[mi][nj], 0, 0, 0);
  }

  const float* b1 = g == 0 ? b1_0 : g == 1 ? b1_1 : g == 2 ? b1_2 : b1_3;
#pragma unroll
  for (int nj = 0; nj < 4; ++nj) {
    int cl = 64 * wn + 16 * nj + r;
    float bias = b1[cl];
    int Cg = 128 * g + cl;
    int kkd = Cg >> 5;
    int lane2hi = ((Cg >> 3) & 3) << 4;
    int j2 = Cg & 7;
#pragma unroll
    for (int mi = 0; mi < 4; ++mi) {
#pragma unroll
      for (int v = 0; v < 4; ++v) {
        int R = 128 * bi + 64 * wm + 16 * mi + 4 * q + v;
        float val = fmaxf(s[mi][nj][v] + bias, 0.0f);
        int mb = R >> 4;
        int lane2 = lane2hi | (R & 15);
        hfrag[((size_t)((mb * 16 + kkd) * 64 + lane2)) * 8 + j2] = f2bf(val);
      }
    }
  }
}

// --------------------- stage A2: lat_g = H_g@W2_g + b2 -----------------------
__global__ __launch_bounds__(256) void k_gemm2(
    const unsigned short* __restrict__ hfrag, const unsigned short* __restrict__ w2f,
    const float* __restrict__ b2_0, const float* __restrict__ b2_1,
    const float* __restrict__ b2_2, const float* __restrict__ b2_3,
    unsigned short* __restrict__ latf) {
  int bi = blockIdx.x, g = blockIdx.y;
  int lane = threadIdx.x & 63, w = threadIdx.x >> 6;
  int wm = w >> 1, wn = w & 1;
  int q = lane >> 4, r = lane & 15;
  int mbase = 8 * bi + 4 * wm;

  f32x4 s[4][4];
#pragma unroll
  for (int mi = 0; mi < 4; ++mi)
#pragma unroll
    for (int nj = 0; nj < 4; ++nj) s[mi][nj] = (f32x4){0.f, 0.f, 0.f, 0.f};

#pragma unroll
  for (int kk = 0; kk < 4; ++kk) {
    short8 a[4], b[4];
#pragma unroll
    for (int mi = 0; mi < 4; ++mi)
      a[mi] = *reinterpret_cast<const short8*>(
          hfrag + ((size_t)(((mbase + mi) * 16 + 4 * g + kk) * 64 + lane)) * 8);
#pragma unroll
    for (int nj = 0; nj < 4; ++nj)
      b[nj] = *reinterpret_cast<const short8*>(
          w2f + ((size_t)(((g * 4 + kk) * 8 + 4 * wn + nj) * 64 + lane)) * 8);
#pragma unroll
    for (int mi = 0; mi < 4; ++mi)
#pragma unroll
      for (int nj = 0; nj < 4; ++nj)
        s[mi][nj] = __builtin_amdgcn_mfma_f32_16x16x32_bf16(a[mi], b[nj], s[mi][nj], 0, 0, 0);
  }

  const float* b2 = g == 0 ? b2_0 : g == 1 ? b2_1 : g == 2 ? b2_2 : b2_3;
#pragma unroll
  for (int nj = 0; nj < 4; ++nj) {
    int cl = 64 * wn + 16 * nj + r;
    float bias = b2[cl];
    int kkd = cl >> 5;
    int lane2hi = ((cl >> 3) & 3) << 4;
    int j2 = cl & 7;
#pragma unroll
    for (int mi = 0; mi < 4; ++mi) {
#pragma unroll
      for (int v = 0; v < 4; ++v) {
        int R = 128 * bi + 64 * wm + 16 * mi + 4 * q + v;
        float val = s[mi][nj][v] + bias;
        int mb = R >> 4;
        int lane2 = lane2hi | (R & 15);
        latf[((size_t)(((g * 512 + mb) * 4 + kkd) * 64 + lane2)) * 8 + j2] = f2bf(val);
      }
    }
  }
}

// --------------------------- stage B: fused context --------------------------
// Block: 256 thr / 4 waves sharing one 16-row block (mb = bid>>2), strip
// cs = bid&3 (2048 cols), 32 steps x 64 cols; wave w owns tj = cb0+s*4+w.
// s = mfma(fj, fi): lane(q,r) reg v -> out(16*mb + r, 16*tj + 4q + v).
// fi: 16KB LDS. fj: reg dbuf, ONE PHASE AHEAD. ew: reg dbuf, one step ahead.

#define VLD4(dst, p, OFF) \
  asm volatile("global_load_dwordx4 %0, %1, off offset:" OFF : "=v"(dst) : "v"(p))

#define LOADG(F, BASE, G)                                                     \
  do {                                                                        \
    const unsigned short* _p = (BASE) + (size_t)(G) * GS;                     \
    VLD4(F[0], _p, "0");    VLD4(F[1], _p, "1024");                           \
    VLD4(F[2], _p, "2048"); VLD4(F[3], _p, "3072");                           \
  } while (0)

#define GRAMG(SG, F, G)                                                       \
  do {                                                                        \
    short8 _i0 = ds_read_frag(fib + ((G) * 4 + 0) * 1024u + l16);             \
    short8 _i1 = ds_read_frag(fib + ((G) * 4 + 1) * 1024u + l16);             \
    short8 _i2 = ds_read_frag(fib + ((G) * 4 + 2) * 1024u + l16);             \
    short8 _i3 = ds_read_frag(fib + ((G) * 4 + 3) * 1024u + l16);             \
    asm volatile("s_waitcnt lgkmcnt(0)" ::: "memory");                        \
    __builtin_amdgcn_sched_barrier(0);                                        \
    SG = (f32x4){0.f, 0.f, 0.f, 0.f};                                         \
    SG = __builtin_amdgcn_mfma_f32_16x16x32_bf16(F[0], _i0, SG, 0, 0, 0);     \
    SG = __builtin_amdgcn_mfma_f32_16x16x32_bf16(F[1], _i1, SG, 0, 0, 0);     \
    SG = __builtin_amdgcn_mfma_f32_16x16x32_bf16(F[2], _i2, SG, 0, 0, 0);     \
    SG = __builtin_amdgcn_mfma_f32_16x16x32_bf16(F[3], _i3, SG, 0, 0, 0);     \
  } while (0)

// One step. Entry: fjA holds g0 IN FLIGHT (issued one phase ago); EWC regs
// issued one full step ago. Queue on entry: [F0(4), EW(3), ST(1)] = 8.
#define STEP(S, EWCa, EWCm, EWCj, EWNa, EWNm, EWNj)                           \
  do {                                                                        \
    const unsigned short* fjbase =                                            \
        latf + (size_t)(cb0 + (S) * 4 + w) * 2048 + (size_t)lane * 8;         \
    f32x4 sg, o4;                                                             \
    /* phase0: g0 (in fjA) */                                                 \
    LOADG(fjB, fjbase, 1);                                                    \
    asm volatile("s_waitcnt vmcnt(8)" ::: "memory");                          \
    __builtin_amdgcn_sched_barrier(0);                                        \
    GRAMG(sg, fjA, 0);                                                        \
    o4[0] = w0 * sigf(sg[0]); o4[1] = w0 * sigf(sg[1]);                       \
    o4[2] = w0 * sigf(sg[2]); o4[3] = w0 * sigf(sg[3]);                       \
    /* phase1: g1 (in fjB) */                                                 \
    LOADG(fjA, fjbase, 2);                                                    \
    asm volatile("s_waitcnt vmcnt(4)" ::: "memory");                          \
    __builtin_amdgcn_sched_barrier(0);                                        \
    GRAMG(sg, fjB, 1);                                                        \
    o4[0] += w1 * sigf(sg[0] * EWCa[0]); o4[1] += w1 * sigf(sg[1] * EWCa[1]); \
    o4[2] += w1 * sigf(sg[2] * EWCa[2]); o4[3] += w1 * sigf(sg[3] * EWCa[3]); \
    /* phase2: g2 (in fjA) */                                                 \
    LOADG(fjB, fjbase, 3);                                                    \
    asm volatile("s_waitcnt vmcnt(4)" ::: "memory");                          \
    __builtin_amdgcn_sched_barrier(0);                                        \
    GRAMG(sg, fjA, 2);                                                        \
    o4[0] += w2 * sigf(sg[0] * EWCm[0]); o4[1] += w2 * sigf(sg[1] * EWCm[1]); \
    o4[2] += w2 * sigf(sg[2] * EWCm[2]); o4[3] += w2 * sigf(sg[3] * EWCm[3]); \
    /* phase3: issue next-step g0 + ew(s+1), then g3 (in fjB) */              \
    {                                                                         \
      const unsigned short* _nb = fjbase + 4 * 2048;   /* tj+4; safe overrun */ \
      LOADG(fjA, _nb, 0);                                                     \
      int _sn = ((S) + 1 < 32) ? (S) + 1 : (S);                               \
      const float* _ea = aa + ewoff + (size_t)_sn * 64;                       \
      const float* _em = mod + ewoff + (size_t)_sn * 64;                      \
      const float* _ej = adj + ewoff + (size_t)_sn * 64;                      \
      VLD4(EWNa, _ea, "0"); VLD4(EWNm, _em, "0"); VLD4(EWNj, _ej, "0");       \
    }                                                                         \
    asm volatile("s_waitcnt vmcnt(7)" ::: "memory");                          \
    __builtin_amdgcn_sched_barrier(0);                                        \
    GRAMG(sg, fjB, 3);                                                        \
    f32x4 res;                                                                \
    {                                                                         \
      float u0 = sigf(sg[0]), u1 = sigf(sg[1]);                               \
      float u2 = sigf(sg[2]), u3 = sigf(sg[3]);                               \
      res[0] = EWCj[0] * (o4[0] - u0) + u0;                                   \
      res[1] = EWCj[1] * (o4[1] - u1) + u1;                                   \
      res[2] = EWCj[2] * (o4[2] - u2) + u2;                                   \
      res[3] = EWCj[3] * (o4[3] - u3) + u3;                                   \
    }                                                                         \
    {                                                                         \
      float* _op = out + ewoff + (size_t)(S) * 64;                            \
      asm volatile("global_store_dwordx4 %0, %1, off" ::"v"(_op), "v"(res)    \
                   : "memory");                                               \
    }                                                                         \
  } while (0)

__global__ __launch_bounds__(256, 4) void k_ctx(
    const unsigned short* __restrict__ latf,
    const float* __restrict__ adj, const float* __restrict__ aa,
    const float* __restrict__ mod, const float* __restrict__ wsv,
    float* __restrict__ out) {
  __shared__ unsigned short fi_lds[8192];   // 16 KB: 16 frags (4g x 4kk)

  const int bid = blockIdx.x;               // 2048 = 512 rowblocks x 4 strips
  const int cs = bid & 3;
  const int mb = bid >> 2;                  // 16-row block (0..511)
  const int lane = threadIdx.x & 63, w = threadIdx.x >> 6;
  const int q = lane >> 4, r = lane & 15;

  // softmax(ws)
  float s0w = wsv[0], s1w = wsv[1], s2w = wsv[2];
  float mx = fmaxf(fmaxf(s0w, s1w), s2w);
  float e0 = __builtin_amdgcn_exp2f(1.4426950408889634f * (s0w - mx));
  float e1 = __builtin_amdgcn_exp2f(1.4426950408889634f * (s1w - mx));
  float e2 = __builtin_amdgcn_exp2f(1.4426950408889634f * (s2w - mx));
  float inv = __builtin_amdgcn_rcpf(e0 + e1 + e2);
  float w0 = e0 * inv, w1 = e1 * inv, w2 = e2 * inv;

  const size_t GS = (size_t)512 * 2048;     // latf elements per latent
  const int cb0 = cs * 128;                 // first col-block of strip

  // ew per-lane offset: row = 16*mb + r, col = cs*2048 + 16w + 4q (+64/step)
  const size_t ewoff = (size_t)(mb * 16 + r) * 8192 + (size_t)cs * 2048
                     + (size_t)(16 * w + 4 * q);

  // ---- prologue: stage fi (wave w -> gram w's 4 frags); prime fj(g0), ew ----
#pragma unroll
  for (int kk = 0; kk < 4; ++kk)
    gload_lds16u(latf + GS * w + (size_t)(mb * 4 + kk) * 512 + lane * 8,
                 &fi_lds[(w * 4 + kk) * 512]);

  short8 fjA[4], fjB[4];
  f32x4 ewAa, ewAm, ewAj, ewBa, ewBm, ewBj;
  {
    const unsigned short* fjbase0 =
        latf + (size_t)(cb0 + w) * 2048 + (size_t)lane * 8;
    LOADG(fjA, fjbase0, 0);
  }
  VLD4(ewAa, (aa + ewoff), "0");
  VLD4(ewAm, (mod + ewoff), "0");
  VLD4(ewAj, (adj + ewoff), "0");
  asm volatile("s_waitcnt vmcnt(0)" ::: "memory");
  __builtin_amdgcn_s_barrier();

  const unsigned fib = lds_off(fi_lds);
  const unsigned l16 = (unsigned)lane * 16u;

#pragma unroll 1
  for (int s = 0; s < 32; s += 2) {
    STEP(s, ewAa, ewAm, ewAj, ewBa, ewBm, ewBj);
    STEP(s + 1, ewBa, ewBm, ewBj, ewAa, ewAm, ewAj);
  }
}

// ------------------------------------------------------------------------------
extern "C" void kernel_launch(void* const* d_in, const int* in_sizes, int n_in,
                              void* d_out, int out_size, void* d_ws, size_t ws_size,
                              hipStream_t stream) {
  const float* feat = (const float*)d_in[0];
  const float* adj  = (const float*)d_in[1];
  const float* aa   = (const float*)d_in[2];
  const float* mod  = (const float*)d_in[3];
  // g order: 0=link, 1=aa, 2=mod, 3=unlink
  const float* W1g[4] = {(const float*)d_in[4], (const float*)d_in[12],
                         (const float*)d_in[16], (const float*)d_in[8]};
  const float* b1g[4] = {(const float*)d_in[5], (const float*)d_in[13],
                         (const float*)d_in[17], (const float*)d_in[9]};
  const float* W2g[4] = {(const float*)d_in[6], (const float*)d_in[14],
                         (const float*)d_in[18], (const float*)d_in[10]};
  const float* b2g[4] = {(const float*)d_in[7], (const float*)d_in[15],
                         (const float*)d_in[19], (const float*)d_in[11]};
  const float* wsv = (const float*)d_in[20];
  float* out = (float*)d_out;

  // workspace layout (elements of ushort)
  unsigned short* featf = (unsigned short*)d_ws;   // 4,194,304 elems (8 MiB)
  unsigned short* hfrag = featf + 4194304;         // 4,194,304
  unsigned short* latf  = hfrag + 4194304;         // 4,194,304
  unsigned short* w1f   = latf + 4194304;          //   262,144
  unsigned short* w2f   = w1f + 262144;            //    65,536
  if (ws_size < 25821184) return;

  k_featfrag<<<2048, 256, 0, stream>>>(feat, featf);
  k_wfrag<<<160, 256, 0, stream>>>(W1g[0], W1g[1], W1g[2], W1g[3],
                                   W2g[0], W2g[1], W2g[2], W2g[3], w1f, w2f);
  k_gemm1<<<dim3(64, 4), 256, 0, stream>>>(featf, w1f, b1g[0], b1g[1], b1g[2], b1g[3], hfrag);
  k_gemm2<<<dim3(64, 4), 256, 0, stream>>>(hfrag, w2f, b2g[0], b2g[1], b2g[2], b2g[3], latf);
  k_ctx<<<2048, 256, 0, stream>>>(latf, adj, aa, mod, wsv, out);
}

// Round 14
// 370.387 us; speedup vs baseline: 1.2180x; 1.1906x over previous
//
#include <hip/hip_runtime.h>

// ---------------------------------------------------------------------------
// meta_model: out = (w0*sig(Ll Ll^T) + w1*sig((La La^T)*aa) + w2*sig((Lm Lm^T)*mod)
//                    - sig(Lu Lu^T)) * adj + sig(Lu Lu^T)
// with L* = mlp(feat), w = softmax(ws)
//
// R13: cut total TCC byte volume (the last unswept axis). fj fragment
// traffic was 4.3 GB = 80% of all bytes (16 KB/wave-step, zero sharing);
// every schedule at that volume pinned at 2.2-2.9 TB/s HBM-side. Now:
//   - block = 4 waves x 16 rows STACKED = 64 rows; all waves share each
//     step's 16 KB fj via triple-buffered LDS (48 KB) -> fj bytes /4
//   - fi = wave's own 16 frags in asm-pinned VGPRs (R10-proven mapping)
//   - ew = reg double-buffer via asm VLD4 (R11-proven), one step ahead
//   - per step: [4 fj fills(s+1) + 3 ew(s+1)] -> vmcnt(7) (retires own
//     fills(s), ew(s), store(s-1); keeps 7 younger in flight a full step)
//     -> s_barrier -> 16 ds_read + 16 MFMA + sigmoid + asm store
//   - triple buffer + 1 barrier/step => fill target = buffer last read
//     2 steps ago; no race
//   - grid 1024 = 128 rowgroups x 8 strips (cs = bid&7 == XCD); 3 blocks/CU
// ---------------------------------------------------------------------------

typedef __attribute__((ext_vector_type(8))) short short8;
typedef __attribute__((ext_vector_type(4))) float f32x4;

__device__ __forceinline__ unsigned short f2bf(float x) {
  union { float f; unsigned u; } v; v.f = x;
  unsigned u = v.u + 0x7FFFu + ((v.u >> 16) & 1u);   // round-to-nearest-even
  return (unsigned short)(u >> 16);
}

__device__ __forceinline__ float sigf(float x) {
  float e = __builtin_amdgcn_exp2f(-1.4426950408889634f * x);
  return __builtin_amdgcn_rcpf(1.0f + e);
}

__device__ __forceinline__ void gload_lds16u(const unsigned short* g, unsigned short* l) {
  __builtin_amdgcn_global_load_lds(
      (const __attribute__((address_space(1))) void*)g,
      (__attribute__((address_space(3))) void*)l, 16, 0, 0);
}

__device__ __forceinline__ unsigned lds_off(const void* p) {
  return (unsigned)(uintptr_t)(const __attribute__((address_space(3))) void*)p;
}
__device__ __forceinline__ short8 ds_read_frag(unsigned a) {
  short8 d;
  asm volatile("ds_read_b128 %0, %1" : "=v"(d) : "v"(a));
  return d;
}

// --------------------------- stage A0: feat -> frag -------------------------
__global__ __launch_bounds__(256) void k_featfrag(const float* __restrict__ feat,
                                                  unsigned short* __restrict__ dst) {
  int t = blockIdx.x * 256 + threadIdx.x;   // 8192 rows * 64 chunks
  int row = t >> 6, kc = t & 63;            // 8 cols per thread
  const float4* s = reinterpret_cast<const float4*>(feat + row * 512 + kc * 8);
  float4 v0 = s[0], v1 = s[1];
  short8 o;
  o[0] = f2bf(v0.x); o[1] = f2bf(v0.y); o[2] = f2bf(v0.z); o[3] = f2bf(v0.w);
  o[4] = f2bf(v1.x); o[5] = f2bf(v1.y); o[6] = f2bf(v1.z); o[7] = f2bf(v1.w);
  int mb = row >> 4, kk = kc >> 2;
  int lane = ((kc & 3) << 4) | (row & 15);
  *reinterpret_cast<short8*>(dst + ((size_t)((mb * 16 + kk) * 64 + lane)) * 8) = o;
}

// --------------------- stage A0w: W1/W2 -> B-frag layout ---------------------
__global__ __launch_bounds__(256) void k_wfrag(
    const float* __restrict__ w1_0, const float* __restrict__ w1_1,
    const float* __restrict__ w1_2, const float* __restrict__ w1_3,
    const float* __restrict__ w2_0, const float* __restrict__ w2_1,
    const float* __restrict__ w2_2, const float* __restrict__ w2_3,
    unsigned short* __restrict__ w1f, unsigned short* __restrict__ w2f) {
  int t = blockIdx.x * 256 + threadIdx.x;
  if (t < 32768) {  // W1frag: [g][kk=16][nb=8][lane=64][j=8]
    int lane = t & 63, nb = (t >> 6) & 7, kk = (t >> 9) & 15, g = t >> 13;
    const float* W = g == 0 ? w1_0 : g == 1 ? w1_1 : g == 2 ? w1_2 : w1_3;
    int q = lane >> 4, r = lane & 15;
    int col = nb * 16 + r;
    short8 o;
#pragma unroll
    for (int j = 0; j < 8; ++j) o[j] = f2bf(W[(kk * 32 + q * 8 + j) * 128 + col]);
    *reinterpret_cast<short8*>(w1f + (size_t)t * 8) = o;
  } else if (t < 40960) {  // W2frag: [g][kk=4][nb=8][lane=64][j=8]
    int t2 = t - 32768;
    int lane = t2 & 63, nb = (t2 >> 6) & 7, kk = (t2 >> 9) & 3, g = t2 >> 11;
    const float* W = g == 0 ? w2_0 : g == 1 ? w2_1 : g == 2 ? w2_2 : w2_3;
    int q = lane >> 4, r = lane & 15;
    int col = nb * 16 + r;
    short8 o;
#pragma unroll
    for (int j = 0; j < 8; ++j) o[j] = f2bf(W[(kk * 32 + q * 8 + j) * 128 + col]);
    *reinterpret_cast<short8*>(w2f + (size_t)t2 * 8) = o;
  }
}

// --------------------- stage A1: H = relu(feat@W1cat + b1) -------------------
__global__ __launch_bounds__(256) void k_gemm1(
    const unsigned short* __restrict__ featf, const unsigned short* __restrict__ w1f,
    const float* __restrict__ b1_0, const float* __restrict__ b1_1,
    const float* __restrict__ b1_2, const float* __restrict__ b1_3,
    unsigned short* __restrict__ hfrag) {
  int bi = blockIdx.x, g = blockIdx.y;
  int lane = threadIdx.x & 63, w = threadIdx.x >> 6;
  int wm = w >> 1, wn = w & 1;
  int q = lane >> 4, r = lane & 15;
  int mbase = 8 * bi + 4 * wm;

  f32x4 s[4][4];
#pragma unroll
  for (int mi = 0; mi < 4; ++mi)
#pragma unroll
    for (int nj = 0; nj < 4; ++nj) s[mi][nj] = (f32x4){0.f, 0.f, 0.f, 0.f};

  for (int kk = 0; kk < 16; ++kk) {
    short8 a[4], b[4];
#pragma unroll
    for (int mi = 0; mi < 4; ++mi)
      a[mi] = *reinterpret_cast<const short8*>(
          featf + ((size_t)(((mbase + mi) * 16 + kk) * 64 + lane)) * 8);
#pragma unroll
    for (int nj = 0; nj < 4; ++nj)
      b[nj] = *reinterpret_cast<const short8*>(
          w1f + ((size_t)(((g * 16 + kk) * 8 + 4 * wn + nj) * 64 + lane)) * 8);
#pragma unroll
    for (int mi = 0; mi < 4; ++mi)
#pragma unroll
      for (int nj = 0; nj < 4; ++nj)
        s[mi][nj] = __builtin_amdgcn_mfma_f32_16x16x32_bf16(a[mi], b[nj], s[mi][nj], 0, 0, 0);
  }

  const float* b1 = g == 0 ? b1_0 : g == 1 ? b1_1 : g == 2 ? b1_2 : b1_3;
#pragma unroll
  for (int nj = 0; nj < 4; ++nj) {
    int cl = 64 * wn + 16 * nj + r;
    float bias = b1[cl];
    int Cg = 128 * g + cl;
    int kkd = Cg >> 5;
    int lane2hi = ((Cg >> 3) & 3) << 4;
    int j2 = Cg & 7;
#pragma unroll
    for (int mi = 0; mi < 4; ++mi) {
#pragma unroll
      for (int v = 0; v < 4; ++v) {
        int R = 128 * bi + 64 * wm + 16 * mi + 4 * q + v;
        float val = fmaxf(s[mi][nj][v] + bias, 0.0f);
        int mb = R >> 4;
        int lane2 = lane2hi | (R & 15);
        hfrag[((size_t)((mb * 16 + kkd) * 64 + lane2)) * 8 + j2] = f2bf(val);
      }
    }
  }
}

// --------------------- stage A2: lat_g = H_g@W2_g + b2 -----------------------
__global__ __launch_bounds__(256) void k_gemm2(
    const unsigned short* __restrict__ hfrag, const unsigned short* __restrict__ w2f,
    const float* __restrict__ b2_0, const float* __restrict__ b2_1,
    const float* __restrict__ b2_2, const float* __restrict__ b2_3,
    unsigned short* __restrict__ latf) {
  int bi = blockIdx.x, g = blockIdx.y;
  int lane = threadIdx.x & 63, w = threadIdx.x >> 6;
  int wm = w >> 1, wn = w & 1;
  int q = lane >> 4, r = lane & 15;
  int mbase = 8 * bi + 4 * wm;

  f32x4 s[4][4];
#pragma unroll
  for (int mi = 0; mi < 4; ++mi)
#pragma unroll
    for (int nj = 0; nj < 4; ++nj) s[mi][nj] = (f32x4){0.f, 0.f, 0.f, 0.f};

#pragma unroll
  for (int kk = 0; kk < 4; ++kk) {
    short8 a[4], b[4];
#pragma unroll
    for (int mi = 0; mi < 4; ++mi)
      a[mi] = *reinterpret_cast<const short8*>(
          hfrag + ((size_t)(((mbase + mi) * 16 + 4 * g + kk) * 64 + lane)) * 8);
#pragma unroll
    for (int nj = 0; nj < 4; ++nj)
      b[nj] = *reinterpret_cast<const short8*>(
          w2f + ((size_t)(((g * 4 + kk) * 8 + 4 * wn + nj) * 64 + lane)) * 8);
#pragma unroll
    for (int mi = 0; mi < 4; ++mi)
#pragma unroll
      for (int nj = 0; nj < 4; ++nj)
        s[mi][nj] = __builtin_amdgcn_mfma_f32_16x16x32_bf16(a[mi], b[nj], s[mi][nj], 0, 0, 0);
  }

  const float* b2 = g == 0 ? b2_0 : g == 1 ? b2_1 : g == 2 ? b2_2 : b2_3;
#pragma unroll
  for (int nj = 0; nj < 4; ++nj) {
    int cl = 64 * wn + 16 * nj + r;
    float bias = b2[cl];
    int kkd = cl >> 5;
    int lane2hi = ((cl >> 3) & 3) << 4;
    int j2 = cl & 7;
#pragma unroll
    for (int mi = 0; mi < 4; ++mi) {
#pragma unroll
      for (int v = 0; v < 4; ++v) {
        int R = 128 * bi + 64 * wm + 16 * mi + 4 * q + v;
        float val = s[mi][nj][v] + bias;
        int mb = R >> 4;
        int lane2 = lane2hi | (R & 15);
        latf[((size_t)(((g * 512 + mb) * 4 + kkd) * 64 + lane2)) * 8 + j2] = f2bf(val);
      }
    }
  }
}

// --------------------------- stage B: fused context --------------------------
// Block: 256 thr / 4 waves x 16 rows STACKED (mb = rb*4 + w); all waves share
// col tile tj = cs*64 + s per step, 64 steps. s = mfma(fj, fi):
// lane(q,r) reg v -> out(16*mb + r, 16*tj + 4q + v).
// fj: LDS triple buffer (16 KB/step, filled 1 step ahead, 4 fills/wave).
// fi: 16 asm-pinned VGPR frags. ew: reg double buffer (asm VLD4).

#define FILD(dst, p, OFF) \
  asm volatile("global_load_dwordx4 %0, %1, off offset:" OFF : "=v"(dst) : "v"(p))
#define VLD4(dst, p, OFF) \
  asm volatile("global_load_dwordx4 %0, %1, off offset:" OFF : "=v"(dst) : "v"(p))

#define GRAMF(SG, G, FJC)                                                     \
  do {                                                                        \
    short8 _j0 = ds_read_frag((FJC) + ((G) * 4 + 0) * 1024u + l16);           \
    short8 _j1 = ds_read_frag((FJC) + ((G) * 4 + 1) * 1024u + l16);           \
    short8 _j2 = ds_read_frag((FJC) + ((G) * 4 + 2) * 1024u + l16);           \
    short8 _j3 = ds_read_frag((FJC) + ((G) * 4 + 3) * 1024u + l16);           \
    asm volatile("s_waitcnt lgkmcnt(0)" ::: "memory");                        \
    __builtin_amdgcn_sched_barrier(0);                                        \
    SG = (f32x4){0.f, 0.f, 0.f, 0.f};                                         \
    SG = __builtin_amdgcn_mfma_f32_16x16x32_bf16(_j0, fi[G][0], SG, 0, 0, 0); \
    SG = __builtin_amdgcn_mfma_f32_16x16x32_bf16(_j1, fi[G][1], SG, 0, 0, 0); \
    SG = __builtin_amdgcn_mfma_f32_16x16x32_bf16(_j2, fi[G][2], SG, 0, 0, 0); \
    SG = __builtin_amdgcn_mfma_f32_16x16x32_bf16(_j3, fi[G][3], SG, 0, 0, 0); \
  } while (0)

// One step. Entry queue: [fills(S)4, ew(S)3, store(S-1)1] = 8 (0 at S=0).
#define STEP(S, EWCa, EWCm, EWCj, EWNa, EWNm, EWNj)                           \
  do {                                                                        \
    int _bf = (br == 2) ? 0 : br + 1;                                         \
    int _sn = ((S) < 63) ? (S) + 1 : 63;                                      \
    {                                                                         \
      const unsigned short* _fp = latf + GS * w                               \
          + ((size_t)((tj0 + _sn) * 4) << 9) + (size_t)lane * 8;              \
      gload_lds16u(_fp,        &fj_lds[_bf][w * 4 + 0][0]);                   \
      gload_lds16u(_fp + 512,  &fj_lds[_bf][w * 4 + 1][0]);                   \
      gload_lds16u(_fp + 1024, &fj_lds[_bf][w * 4 + 2][0]);                   \
      gload_lds16u(_fp + 1536, &fj_lds[_bf][w * 4 + 3][0]);                   \
      VLD4(EWNa, (aa + ewoff + (size_t)_sn * 16), "0");                       \
      VLD4(EWNm, (mod + ewoff + (size_t)_sn * 16), "0");                      \
      VLD4(EWNj, (adj + ewoff + (size_t)_sn * 16), "0");                      \
    }                                                                         \
    __builtin_amdgcn_sched_barrier(0);                                        \
    /* retire own fills(S)+ew(S)+store(S-1); keep 7 younger in flight */      \
    asm volatile("s_waitcnt vmcnt(7)" ::: "memory");                          \
    __builtin_amdgcn_s_barrier();                                             \
    const unsigned _fjc = fjb + (unsigned)br * 16384u;                        \
    f32x4 sg, o4;                                                             \
    GRAMF(sg, 0, _fjc);                                                       \
    o4[0] = w0 * sigf(sg[0]); o4[1] = w0 * sigf(sg[1]);                       \
    o4[2] = w0 * sigf(sg[2]); o4[3] = w0 * sigf(sg[3]);                       \
    GRAMF(sg, 1, _fjc);                                                       \
    o4[0] += w1 * sigf(sg[0] * EWCa[0]); o4[1] += w1 * sigf(sg[1] * EWCa[1]); \
    o4[2] += w1 * sigf(sg[2] * EWCa[2]); o4[3] += w1 * sigf(sg[3] * EWCa[3]); \
    GRAMF(sg, 2, _fjc);                                                       \
    o4[0] += w2 * sigf(sg[0] * EWCm[0]); o4[1] += w2 * sigf(sg[1] * EWCm[1]); \
    o4[2] += w2 * sigf(sg[2] * EWCm[2]); o4[3] += w2 * sigf(sg[3] * EWCm[3]); \
    GRAMF(sg, 3, _fjc);                                                       \
    f32x4 res;                                                                \
    {                                                                         \
      float u0 = sigf(sg[0]), u1 = sigf(sg[1]);                               \
      float u2 = sigf(sg[2]), u3 = sigf(sg[3]);                               \
      res[0] = EWCj[0] * (o4[0] - u0) + u0;                                   \
      res[1] = EWCj[1] * (o4[1] - u1) + u1;                                   \
      res[2] = EWCj[2] * (o4[2] - u2) + u2;                                   \
      res[3] = EWCj[3] * (o4[3] - u3) + u3;                                   \
    }                                                                         \
    {                                                                         \
      float* _op = out + ewoff + (size_t)(S) * 16;                            \
      asm volatile("global_store_dwordx4 %0, %1, off" ::"v"(_op), "v"(res)    \
                   : "memory");                                               \
    }                                                                         \
    br = _bf;                                                                 \
  } while (0)

__global__ __launch_bounds__(256, 3) void k_ctx(
    const unsigned short* __restrict__ latf,
    const float* __restrict__ adj, const float* __restrict__ aa,
    const float* __restrict__ mod, const float* __restrict__ wsv,
    float* __restrict__ out) {
  __shared__ unsigned short fj_lds[3][16][512];   // 48 KB triple buffer

  const int bid = blockIdx.x;               // 1024 = 128 rowgroups x 8 strips
  const int cs = bid & 7;                   // strip == XCD under round-robin
  const int rb = bid >> 3;                  // 64-row group (0..127)
  const int lane = threadIdx.x & 63, w = threadIdx.x >> 6;
  const int q = lane >> 4, r = lane & 15;
  const int mb = rb * 4 + w;                // wave's 16-row block (0..511)

  // softmax(ws)
  float s0w = wsv[0], s1w = wsv[1], s2w = wsv[2];
  float mx = fmaxf(fmaxf(s0w, s1w), s2w);
  float e0 = __builtin_amdgcn_exp2f(1.4426950408889634f * (s0w - mx));
  float e1 = __builtin_amdgcn_exp2f(1.4426950408889634f * (s1w - mx));
  float e2 = __builtin_amdgcn_exp2f(1.4426950408889634f * (s2w - mx));
  float inv = __builtin_amdgcn_rcpf(e0 + e1 + e2);
  float w0 = e0 * inv, w1 = e1 * inv, w2 = e2 * inv;

  const size_t GS = (size_t)512 * 2048;     // latf elements per latent
  const int tj0 = cs * 64;                  // first col tile of strip

  // ew per-lane offset: row = 16*mb + r, col = cs*1024 + 4q (+16/step)
  const size_t ewoff = (size_t)(mb * 16 + r) * 8192 + (size_t)cs * 1024
                     + (size_t)(4 * q);

  // ---- fi: wave's 16 rows, 4g x 4kk = 16 frags pinned via asm loads ----
  short8 fi[4][4];
  {
    const unsigned short* p0 = latf + ((size_t)(mb * 4) << 9) + (size_t)lane * 8;
    FILD(fi[0][0], p0, "0");    FILD(fi[0][1], p0, "1024");
    FILD(fi[0][2], p0, "2048"); FILD(fi[0][3], p0, "3072");
    p0 += GS;
    FILD(fi[1][0], p0, "0");    FILD(fi[1][1], p0, "1024");
    FILD(fi[1][2], p0, "2048"); FILD(fi[1][3], p0, "3072");
    p0 += GS;
    FILD(fi[2][0], p0, "0");    FILD(fi[2][1], p0, "1024");
    FILD(fi[2][2], p0, "2048"); FILD(fi[2][3], p0, "3072");
    p0 += GS;
    FILD(fi[3][0], p0, "0");    FILD(fi[3][1], p0, "1024");
    FILD(fi[3][2], p0, "2048"); FILD(fi[3][3], p0, "3072");
  }

  // ---- prologue: fj(0) -> buf 0 (wave w fills g=w's 4 frags); ew(0) ----
  {
    const unsigned short* fp = latf + GS * w
        + ((size_t)(tj0 * 4) << 9) + (size_t)lane * 8;
    gload_lds16u(fp,        &fj_lds[0][w * 4 + 0][0]);
    gload_lds16u(fp + 512,  &fj_lds[0][w * 4 + 1][0]);
    gload_lds16u(fp + 1024, &fj_lds[0][w * 4 + 2][0]);
    gload_lds16u(fp + 1536, &fj_lds[0][w * 4 + 3][0]);
  }
  f32x4 ewAa, ewAm, ewAj, ewBa, ewBm, ewBj;
  VLD4(ewAa, (aa + ewoff), "0");
  VLD4(ewAm, (mod + ewoff), "0");
  VLD4(ewAj, (adj + ewoff), "0");
  asm volatile("s_waitcnt vmcnt(0)" ::: "memory");
  __builtin_amdgcn_s_barrier();

  const unsigned fjb = lds_off(fj_lds);
  const unsigned l16 = (unsigned)lane * 16u;
  int br = 0;

#pragma unroll 1
  for (int s = 0; s < 64; s += 2) {
    STEP(s, ewAa, ewAm, ewAj, ewBa, ewBm, ewBj);
    STEP(s + 1, ewBa, ewBm, ewBj, ewAa, ewAm, ewAj);
  }
}

// ------------------------------------------------------------------------------
extern "C" void kernel_launch(void* const* d_in, const int* in_sizes, int n_in,
                              void* d_out, int out_size, void* d_ws, size_t ws_size,
                              hipStream_t stream) {
  const float* feat = (const float*)d_in[0];
  const float* adj  = (const float*)d_in[1];
  const float* aa   = (const float*)d_in[2];
  const float* mod  = (const float*)d_in[3];
  // g order: 0=link, 1=aa, 2=mod, 3=unlink
  const float* W1g[4] = {(const float*)d_in[4], (const float*)d_in[12],
                         (const float*)d_in[16], (const float*)d_in[8]};
  const float* b1g[4] = {(const float*)d_in[5], (const float*)d_in[13],
                         (const float*)d_in[17], (const float*)d_in[9]};
  const float* W2g[4] = {(const float*)d_in[6], (const float*)d_in[14],
                         (const float*)d_in[18], (const float*)d_in[10]};
  const float* b2g[4] = {(const float*)d_in[7], (const float*)d_in[15],
                         (const float*)d_in[19], (const float*)d_in[11]};
  const float* wsv = (const float*)d_in[20];
  float* out = (float*)d_out;

  // workspace layout (elements of ushort)
  unsigned short* featf = (unsigned short*)d_ws;   // 4,194,304 elems (8 MiB)
  unsigned short* hfrag = featf + 4194304;         // 4,194,304
  unsigned short* latf  = hfrag + 4194304;         // 4,194,304
  unsigned short* w1f   = latf + 4194304;          //   262,144
  unsigned short* w2f   = w1f + 262144;            //    65,536
  if (ws_size < 25821184) return;

  k_featfrag<<<2048, 256, 0, stream>>>(feat, featf);
  k_wfrag<<<160, 256, 0, stream>>>(W1g[0], W1g[1], W1g[2], W1g[3],
                                   W2g[0], W2g[1], W2g[2], W2g[3], w1f, w2f);
  k_gemm1<<<dim3(64, 4), 256, 0, stream>>>(featf, w1f, b1g[0], b1g[1], b1g[2], b1g[3], hfrag);
  k_gemm2<<<dim3(64, 4), 256, 0, stream>>>(hfrag, w2f, b2g[0], b2g[1], b2g[2], b2g[3], latf);
  k_ctx<<<1024, 256, 0, stream>>>(latf, adj, aa, mod, wsv, out);
}